// Round 4
// baseline (7502.567 us; speedup 1.0000x reference)
//
#include <hip/hip_runtime.h>
#include <cstdint>
#include <cstddef>

// MessagePassing (SCNN-style): 4 sequential directional scans.
// B=16 C=128 H=72 W=200 K=9 pad=4, fp32 in/out.
//
// Round-2: MFMA engine (split-fp16, 3-term: Whi*Ahi + Whi*Alo + Wlo*Ahi).
// Round-3: relaxed agent-scope atomics for cross-block data. 6577us, 0.25. PASS.
// Round-4/5 (FAILED 0.5 / 1.125): both split (b,jc) ownership across 2 blocks.
//   Round-5's math was audited bit-identical -> failure is NOT reassociation.
//   Revised theory: relaxed flag protocol races -- sc1 write-through store ack
//   (vmcnt) is from the XCD egress, not the MALL; flag (different TCC channel)
//   can arrive first; consumer reads stale. Exposure ~ cross-block data volume:
//   round-3 (4-col halos) survived, rounds 4-5 (full 64-co half) died.
// Round-6 (this): EXACT round-3 decomposition (1 block per (b,jc), 8 waves,
//   known-good) + only non-numeric changes:
//   1. flag store RELEASE/AGENT (wbl2 near-free: no dirty L2 lines, all data
//      stores are sc1 write-through). Spin stays RELAXED (no buffer_inv).
//   2. launch_bounds(512,2) + asm pin of ahi[36] -> weights register-resident
//      (round-3 VGPR=128 < 144 proves whi was re-fetched every step = the
//      dominant per-step stall). 1 block/CU: H 208<=256, W 80 co-resident.
//   3. win transposed [wi][ci] pad-130 + float2 phase-2 reads (bit-neutral,
//      fh/fl contents identical) -> kills 4-way stride-50 LDS conflict (4e7cy).

#define B_ 16
#define C_ 128
#define H_ 72
#define W_ 200
#define KW 9
#define NTOT (B_ * C_ * H_ * W_)

using f16x8 = _Float16 __attribute__((ext_vector_type(8)));
using f32x4 = float __attribute__((ext_vector_type(4)));

__device__ __forceinline__ unsigned pack_h2(_Float16 lo, _Float16 hi) {
  unsigned short a = __builtin_bit_cast(unsigned short, lo);
  unsigned short b = __builtin_bit_cast(unsigned short, hi);
  return (unsigned)a | ((unsigned)b << 16);
}

// device-coherent (MALL) access, no cache-wide maintenance ops
__device__ __forceinline__ float dev_load(const float* p) {
  return __hip_atomic_load(p, __ATOMIC_RELAXED, __HIP_MEMORY_SCOPE_AGENT);
}
__device__ __forceinline__ void dev_store(float* p, float v) {
  __hip_atomic_store(p, v, __ATOMIC_RELAXED, __HIP_MEMORY_SCOPE_AGENT);
}

// ---------------- copy x -> out ----------------
__global__ void copy_f4(const float4* __restrict__ src, float4* __restrict__ dst, int n4) {
  int i = blockIdx.x * blockDim.x + threadIdx.x;
  const int stride = gridDim.x * blockDim.x;
  for (; i < n4; i += stride) dst[i] = src[i];
}

// ---------------- transpose last two dims ----------------
template <int SH, int SW>
__global__ void transpose_hw(const float* __restrict__ src, float* __restrict__ dst) {
  __shared__ float t[32][33];
  const size_t base = (size_t)blockIdx.z * SH * SW;
  const int x = blockIdx.x * 32 + threadIdx.x;
#pragma unroll
  for (int j = 0; j < 4; ++j) {
    const int y = blockIdx.y * 32 + threadIdx.y + j * 8;
    if (y < SH && x < SW) t[threadIdx.y + j * 8][threadIdx.x] = src[base + (size_t)y * SW + x];
  }
  __syncthreads();
  const int x2 = blockIdx.y * 32 + threadIdx.x;
#pragma unroll
  for (int j = 0; j < 4; ++j) {
    const int y2 = blockIdx.x * 32 + threadIdx.y + j * 8;
    if (y2 < SW && x2 < SH) dst[base + (size_t)y2 * SH + x2] = t[threadIdx.x][threadIdx.y + j * 8];
  }
}

// ---------------- weight repack: wgt[co][ci][dk] -> MFMA A-frag order ----------------
// frag index: [cot(8)][t(36)][lane(64)] f16x8; lane: m=lane&15 (co), q=lane>>4;
// element j <-> k = t*32 + q*8 + j, k = dk*128 + ci (dk = t>>2, ci = (t&3)*32 + q*8 + j)
__global__ void repack_w(const float* __restrict__ wgt, f16x8* __restrict__ whi,
                         f16x8* __restrict__ wlo) {
  const int blk = blockIdx.x;  // cot*36 + t
  const int cot = blk / 36, t = blk % 36;
  const int lane = threadIdx.x;
  const int n = lane & 15, q = lane >> 4;
  const int co = cot * 16 + n, dk = t >> 2, ci0 = (t & 3) * 32 + q * 8;
  f16x8 h, l;
#pragma unroll
  for (int j = 0; j < 8; ++j) {
    const float w = wgt[((size_t)co * C_ + ci0 + j) * KW + dk];
    const _Float16 hh = (_Float16)w;
    h[j] = hh;
    l[j] = (_Float16)(w - (float)hh);
  }
  whi[(size_t)blk * 64 + lane] = h;
  wlo[(size_t)blk * 64 + lane] = l;
}

// ---------------- MFMA scan pass ----------------
// data[b][c][RDIM][WDIM]; scan RDIM rows; conv (K=9,pad4) over contiguous WDIM.
// grid = 16*NCH blocks: b = bx&15, chunk jc = bx>>4 (16 positions).
template <int RDIM, int WDIM, int NCH>
__global__ __launch_bounds__(512, 2) void pass_mfma(float* __restrict__ data,
                                                    const f16x8* __restrict__ whi,
                                                    const f16x8* __restrict__ wlo,
                                                    unsigned* flags, const int dir) {
  constexpr int RW = RDIM * WDIM;
  __shared__ __align__(16) float win[24 * 130];   // [wi][ci pad 130]
  __shared__ __align__(16) unsigned fh[24 * 68];  // [wi][ci-pair pad 68] fp16 hi
  __shared__ __align__(16) unsigned fl[24 * 68];  // lo plane

  const int tid = threadIdx.x;
  const int wave = tid >> 6, lane = tid & 63;
  const int n = lane & 15, q = lane >> 4;
  const int b = blockIdx.x & 15, jc = blockIdx.x >> 4;
  const int pos_base = jc * 16;
  const size_t bbase = (size_t)b * C_ * RW;

  // persistent A-frags (Whi) in VGPRs: 36 x 4 VGPR = 144.
  // asm pin: makes rematerialization (re-loading whi inside the s-loop)
  // illegal -> compiler must keep them register-resident (cap 256 via
  // launch_bounds(512,2); ~210 total expected).
  f16x8 ahi[36];
#pragma unroll
  for (int t = 0; t < 36; ++t) ahi[t] = whi[(size_t)(wave * 36 + t) * 64 + lane];
#pragma unroll
  for (int t = 0; t < 36; ++t) asm volatile("" : "+v"(ahi[t]));
  const f16x8* wloL = wlo + (size_t)wave * 36 * 64 + lane;

  for (int s = 1; s < RDIM; ++s) {
    const int r = (dir > 0) ? s : (RDIM - 1 - s);
    const int rp = r - dir;  // producer row

    // preload current row r (written only by this block, later this step);
    // issue before the flag spin so MALL latency hides under the wait.
    const int pos = pos_base + n;
    float cur[4];
#pragma unroll
    for (int reg = 0; reg < 4; ++reg) {
      const int co = wave * 16 + q * 4 + reg;
      cur[reg] =
          (pos < WDIM) ? dev_load(&data[bbase + (size_t)co * RW + (size_t)r * WDIM + pos]) : 0.f;
    }

    if (s > 1 && tid < 2) {
      const int jn = jc + (tid ? 1 : -1);
      if (jn >= 0 && jn < NCH) {
        unsigned* f = &flags[((size_t)b * RDIM + rp) * NCH + jn];
        while (__hip_atomic_load(f, __ATOMIC_RELAXED, __HIP_MEMORY_SCOPE_AGENT) == 0u)
          __builtin_amdgcn_s_sleep(1);
        // producer used RELEASE on the flag -> its data is at the coherence
        // point; our data loads are sc1 (bypass stale caches); control dep +
        // __syncthreads orders them after the observation.
      }
    }
    __syncthreads();

    // phase 1: global row rp window [pos_base-4, pos_base+20) -> win[wi][ci]
#pragma unroll
    for (int i = 0; i < 6; ++i) {
      const int idx = tid + 512 * i;  // 3072 = 128ci * 24wi
      const int ci = idx / 24, wi = idx - ci * 24;
      const int p = pos_base - 4 + wi;
      float v = 0.f;
      if (p >= 0 && p < WDIM) v = dev_load(&data[bbase + (size_t)ci * RW + (size_t)rp * WDIM + p]);
      win[wi * 130 + ci] = v;  // stride 130: 2-way banks, free
    }
    __syncthreads();

    // phase 2: split fp32 -> fp16 hi/lo planes [wi][ci-pair];
    // float2 read = stride-2 banks (free). fh/fl contents bit-identical to
    // the round-3 passing kernel (only the win intermediate layout changed).
#pragma unroll
    for (int i = 0; i < 3; ++i) {
      const int idx = tid + 512 * i;  // 1536 = 24wi * 64 ci-pairs
      const int wi = idx >> 6, c2 = idx & 63;
      const float2 xy = *(const float2*)&win[wi * 130 + 2 * c2];
      const _Float16 h0 = (_Float16)xy.x, h1 = (_Float16)xy.y;
      const _Float16 l0 = (_Float16)(xy.x - (float)h0), l1 = (_Float16)(xy.y - (float)h1);
      fh[wi * 68 + c2] = pack_h2(h0, h1);
      fl[wi * 68 + c2] = pack_h2(l0, l1);
    }
    __syncthreads();

    // MFMA: D[co16 x pos16], K = 1152 (36 k-tiles), 3-term split.
    // BIT-EXACT round-3 order: t ascending, 3 separate accumulators.
    f32x4 aA = {0.f, 0.f, 0.f, 0.f}, aB = {0.f, 0.f, 0.f, 0.f}, aC = {0.f, 0.f, 0.f, 0.f};
#pragma unroll
    for (int t = 0; t < 36; ++t) {
      const int dk = t >> 2;
      const int off = (n + dk) * 68 + (t & 3) * 16 + q * 4;  // u32 idx, 16B-aligned
      const f16x8 bh = *(const f16x8*)&fh[off];
      const f16x8 bl = *(const f16x8*)&fl[off];
      const f16x8 al = wloL[(size_t)t * 64];
      aA = __builtin_amdgcn_mfma_f32_16x16x32_f16(ahi[t], bh, aA, 0, 0, 0);
      aB = __builtin_amdgcn_mfma_f32_16x16x32_f16(ahi[t], bl, aB, 0, 0, 0);
      aC = __builtin_amdgcn_mfma_f32_16x16x32_f16(al, bh, aC, 0, 0, 0);
    }

    // epilogue: C/D layout col=lane&15 (pos), row=q*4+reg (co-within-tile)
    if (pos < WDIM) {
#pragma unroll
      for (int reg = 0; reg < 4; ++reg) {
        const int co = wave * 16 + q * 4 + reg;
        const float v = aA[reg] + aB[reg] + aC[reg];
        dev_store(&data[bbase + (size_t)co * RW + (size_t)r * WDIM + pos],
                  cur[reg] + fmaxf(v, 0.f));
      }
    }
    __syncthreads();
    // RELEASE: guarantees the sc1 data stores are visible at the coherence
    // point before the flag is. wbl2 is near-free here (no dirty L2 lines --
    // every global write in this kernel is sc1 write-through).
    if (tid == 0)
      __hip_atomic_store(&flags[((size_t)b * RDIM + r) * NCH + jc], 1u, __ATOMIC_RELEASE,
                         __HIP_MEMORY_SCOPE_AGENT);
  }
}

extern "C" void kernel_launch(void* const* d_in, const int* in_sizes, int n_in, void* d_out,
                              int out_size, void* d_ws, size_t ws_size, hipStream_t stream) {
  const float* x = (const float*)d_in[0];
  const float* w_down = (const float*)d_in[1];
  const float* w_up = (const float*)d_in[2];
  const float* w_right = (const float*)d_in[3];
  const float* w_left = (const float*)d_in[4];
  float* out = (float*)d_out;

  // ---- ws layout ----
  // [0, 256K):        flags (memset 0)
  // [256K, 256K+8*294912): weight frag planes (hi,lo) x 4 passes
  // [2,621,440, ...): transpose scratch T if it fits, else reuse d_in[0]
  unsigned* flags = (unsigned*)d_ws;
  unsigned* f_down = flags;                      // 72*13*16 = 14976
  unsigned* f_up = f_down + H_ * 13 * B_;        // 14976
  unsigned* f_right = f_up + H_ * 13 * B_;       // 200*5*16 = 16000
  unsigned* f_left = f_right + W_ * 5 * B_;      // 16000
  hipMemsetAsync(d_ws, 0, 262144, stream);

  const size_t PLANE = (size_t)8 * 36 * 64;  // f16x8 elements per plane = 294912 B
  f16x8* wf = (f16x8*)((char*)d_ws + 262144);
  f16x8* whi_d = wf + 0 * PLANE;
  f16x8* wlo_d = wf + 1 * PLANE;
  f16x8* whi_u = wf + 2 * PLANE;
  f16x8* wlo_u = wf + 3 * PLANE;
  f16x8* whi_r = wf + 4 * PLANE;
  f16x8* wlo_r = wf + 5 * PLANE;
  f16x8* whi_l = wf + 6 * PLANE;
  f16x8* wlo_l = wf + 7 * PLANE;

  const size_t toff = 262144 + 8 * PLANE * sizeof(f16x8);
  const size_t tbytes = (size_t)NTOT * sizeof(float);
  float* T = (ws_size >= toff + tbytes) ? (float*)((char*)d_ws + toff) : (float*)d_in[0];

  // weight repack (one-time per launch)
  repack_w<<<288, 64, 0, stream>>>(w_down, whi_d, wlo_d);
  repack_w<<<288, 64, 0, stream>>>(w_up, whi_u, wlo_u);
  repack_w<<<288, 64, 0, stream>>>(w_right, whi_r, wlo_r);
  repack_w<<<288, 64, 0, stream>>>(w_left, whi_l, wlo_l);

  // out = x
  copy_f4<<<1024, 256, 0, stream>>>((const float4*)x, (float4*)out, NTOT / 4);

  // down/up: scan h (RDIM=72), conv over w (WDIM=200, 13 chunks) -> 208 blocks
  pass_mfma<H_, W_, 13><<<16 * 13, 512, 0, stream>>>(out, whi_d, wlo_d, f_down, +1);
  pass_mfma<H_, W_, 13><<<16 * 13, 512, 0, stream>>>(out, whi_u, wlo_u, f_up, -1);

  // transpose [b,c,h,w] -> [b,c,w,h]
  {
    dim3 g((W_ + 31) / 32, (H_ + 31) / 32, B_ * C_);
    transpose_hw<H_, W_><<<g, dim3(32, 8), 0, stream>>>(out, T);
  }

  // right/left: scan w (RDIM=200), conv over h (WDIM=72, 5 chunks) -> 80 blocks
  pass_mfma<W_, H_, 5><<<16 * 5, 512, 0, stream>>>(T, whi_r, wlo_r, f_right, +1);
  pass_mfma<W_, H_, 5><<<16 * 5, 512, 0, stream>>>(T, whi_l, wlo_l, f_left, -1);

  // transpose back
  {
    dim3 g((H_ + 31) / 32, (W_ + 31) / 32, B_ * C_);
    transpose_hw<W_, H_><<<g, dim3(32, 8), 0, stream>>>(T, out);
  }
}

// Round 5
// 4634.360 us; speedup vs baseline: 1.6189x; 1.6189x over previous
//
#include <hip/hip_runtime.h>
#include <cstdint>
#include <cstddef>

// MessagePassing (SCNN-style): 4 sequential directional scans.
// B=16 C=128 H=72 W=200 K=9 pad=4, fp32 in/out.
//
// Round-3 (PASS 6577us, 0.25): relaxed agent-scope atomics, 1 block/(b,jc).
// Round-4/5 (FAIL): split (b,jc) ownership across blocks -> do not split.
// Round-6 (PASS 7502us, 0.25): RELEASE flag (+wbl2, -1us/step REGRESSION),
//   asm pin of ahi -> scratch spill (VGPR stayed 128), win transpose -> no
//   conflict change (3.97e7->3.77e7: conflicts are the b128 B-frag floor).
// Round-7 (this): attack the serial handoff chain, keep round-3 protocol.
//   Step-time model (11.3us W): LDS B-frags 2.9us + MFMA 0.5 (overlapped)
//   + ~7us of MALL window loads / flag handoff / 4 barriers.
//   - KEY: 16 of 24 window cols are OUR OWN previous-step outputs ->
//     epilogue now converts res directly into ping-pong fp16 planes in LDS.
//     Per-step MALL loads drop 3072 -> 1024 dwords (8 halo cols only).
//   - cur: plain cached load (row r has no cross-block producer this pass).
//   - 3 barriers/step (was 4); win[] buffer gone.
//   - Flag protocol: EXACT round-3 RELAXED (validated twice, same
//     decomposition, same 4-col halo surface). No pin, launch_bounds(512,1).
//   - All conversions + MFMA order bit-identical -> absmax exactly 0.25.

#define B_ 16
#define C_ 128
#define H_ 72
#define W_ 200
#define KW 9
#define NTOT (B_ * C_ * H_ * W_)

using f16x8 = _Float16 __attribute__((ext_vector_type(8)));
using f32x4 = float __attribute__((ext_vector_type(4)));

__device__ __forceinline__ unsigned pack_h2(_Float16 lo, _Float16 hi) {
  unsigned short a = __builtin_bit_cast(unsigned short, lo);
  unsigned short b = __builtin_bit_cast(unsigned short, hi);
  return (unsigned)a | ((unsigned)b << 16);
}

// device-coherent (MALL) access, no cache-wide maintenance ops
__device__ __forceinline__ float dev_load(const float* p) {
  return __hip_atomic_load(p, __ATOMIC_RELAXED, __HIP_MEMORY_SCOPE_AGENT);
}
__device__ __forceinline__ void dev_store(float* p, float v) {
  __hip_atomic_store(p, v, __ATOMIC_RELAXED, __HIP_MEMORY_SCOPE_AGENT);
}

// ---------------- copy x -> out ----------------
__global__ void copy_f4(const float4* __restrict__ src, float4* __restrict__ dst, int n4) {
  int i = blockIdx.x * blockDim.x + threadIdx.x;
  const int stride = gridDim.x * blockDim.x;
  for (; i < n4; i += stride) dst[i] = src[i];
}

// ---------------- transpose last two dims ----------------
template <int SH, int SW>
__global__ void transpose_hw(const float* __restrict__ src, float* __restrict__ dst) {
  __shared__ float t[32][33];
  const size_t base = (size_t)blockIdx.z * SH * SW;
  const int x = blockIdx.x * 32 + threadIdx.x;
#pragma unroll
  for (int j = 0; j < 4; ++j) {
    const int y = blockIdx.y * 32 + threadIdx.y + j * 8;
    if (y < SH && x < SW) t[threadIdx.y + j * 8][threadIdx.x] = src[base + (size_t)y * SW + x];
  }
  __syncthreads();
  const int x2 = blockIdx.y * 32 + threadIdx.x;
#pragma unroll
  for (int j = 0; j < 4; ++j) {
    const int y2 = blockIdx.x * 32 + threadIdx.y + j * 8;
    if (y2 < SW && x2 < SH) dst[base + (size_t)y2 * SH + x2] = t[threadIdx.x][threadIdx.y + j * 8];
  }
}

// ---------------- weight repack: wgt[co][ci][dk] -> MFMA A-frag order ----------------
// frag index: [cot(8)][t(36)][lane(64)] f16x8; lane: m=lane&15 (co), q=lane>>4;
// element j <-> k = t*32 + q*8 + j, k = dk*128 + ci (dk = t>>2, ci = (t&3)*32 + q*8 + j)
__global__ void repack_w(const float* __restrict__ wgt, f16x8* __restrict__ whi,
                         f16x8* __restrict__ wlo) {
  const int blk = blockIdx.x;  // cot*36 + t
  const int cot = blk / 36, t = blk % 36;
  const int lane = threadIdx.x;
  const int n = lane & 15, q = lane >> 4;
  const int co = cot * 16 + n, dk = t >> 2, ci0 = (t & 3) * 32 + q * 8;
  f16x8 h, l;
#pragma unroll
  for (int j = 0; j < 8; ++j) {
    const float w = wgt[((size_t)co * C_ + ci0 + j) * KW + dk];
    const _Float16 hh = (_Float16)w;
    h[j] = hh;
    l[j] = (_Float16)(w - (float)hh);
  }
  whi[(size_t)blk * 64 + lane] = h;
  wlo[(size_t)blk * 64 + lane] = l;
}

// ---------------- MFMA scan pass ----------------
// data[b][c][RDIM][WDIM]; scan RDIM rows; conv (K=9,pad4) over contiguous WDIM.
// grid = 16*NCH blocks: b = bx&15, chunk jc = bx>>4 (16 positions).
// fp16 planes ping-pong in LDS: buffer (s&1) holds row r's window slice
// [wi 0..23] = pos [pos_base-4, pos_base+20); own cols wi 4..19 written by
// epilogue from registers; halo wi 0..3 / 20..23 fetched from MALL next step.
template <int RDIM, int WDIM, int NCH>
__global__ __launch_bounds__(512, 1) void pass_mfma(float* __restrict__ data,
                                                    const f16x8* __restrict__ whi,
                                                    const f16x8* __restrict__ wlo,
                                                    unsigned* flags, const int dir) {
  constexpr int RW = RDIM * WDIM;
  constexpr int PL = 24 * 68;  // u32 per plane buffer: [wi(24)][ci-pair pad 68]
  __shared__ __align__(16) unsigned fh[2 * PL];
  __shared__ __align__(16) unsigned fl[2 * PL];

  const int tid = threadIdx.x;
  const int wave = tid >> 6, lane = tid & 63;
  const int n = lane & 15, q = lane >> 4;
  const int b = blockIdx.x & 15, jc = blockIdx.x >> 4;
  const int pos_base = jc * 16;
  const int pos = pos_base + n;
  const size_t bbase = (size_t)b * C_ * RW;

  // persistent A-frags (Whi): compiler's choice (round-3 behavior; no pin)
  f16x8 ahi[36];
#pragma unroll
  for (int t = 0; t < 36; ++t) ahi[t] = whi[(size_t)(wave * 36 + t) * 64 + lane];
  const f16x8* wloL = wlo + (size_t)wave * 36 * 64 + lane;

  // ---- init: fill plane buffer 0 with full 24-wi window of row r0 ----
  // row r0 is pre-pass data (written by a previous kernel) -> plain cached.
  {
    const int r0 = (dir > 0) ? 0 : (RDIM - 1);
#pragma unroll
    for (int i = 0; i < 3; ++i) {
      const int idx = tid + 512 * i;  // 1536 = 24 wi * 64 ci-pairs
      const int wi = idx >> 6, c2 = idx & 63;
      const int p = pos_base - 4 + wi;
      float x0 = 0.f, x1 = 0.f;
      if (p >= 0 && p < WDIM) {
        x0 = data[bbase + (size_t)(2 * c2) * RW + (size_t)r0 * WDIM + p];
        x1 = data[bbase + (size_t)(2 * c2 + 1) * RW + (size_t)r0 * WDIM + p];
      }
      const _Float16 h0 = (_Float16)x0, h1 = (_Float16)x1;
      const _Float16 l0 = (_Float16)(x0 - (float)h0), l1 = (_Float16)(x1 - (float)h1);
      fh[wi * 68 + c2] = pack_h2(h0, h1);
      fl[wi * 68 + c2] = pack_h2(l0, l1);
    }
  }

  for (int s = 1; s < RDIM; ++s) {
    const int r = (dir > 0) ? s : (RDIM - 1 - s);
    const int rp = r - dir;          // producer row
    const int pb = (s - 1) & 1;      // plane buffer holding row rp
    const int cb = s & 1;            // plane buffer to fill with row r

    // preload current row r: no cross-block producer within this pass ->
    // plain cached load; issued before the spin to hide latency.
    float cur[4];
#pragma unroll
    for (int reg = 0; reg < 4; ++reg) {
      const int co = wave * 16 + q * 4 + reg;
      cur[reg] = (pos < WDIM) ? data[bbase + (size_t)co * RW + (size_t)r * WDIM + pos] : 0.f;
    }

    if (s > 1 && tid < 2) {
      const int jn = jc + (tid ? 1 : -1);
      if (jn >= 0 && jn < NCH) {
        unsigned* f = &flags[((size_t)b * RDIM + rp) * NCH + jn];
        while (__hip_atomic_load(f, __ATOMIC_RELAXED, __HIP_MEMORY_SCOPE_AGENT) == 0u)
          __builtin_amdgcn_s_sleep(1);
      }
    }
    __syncthreads();  // (A) flags observed

    // halo fill: 8 wi x 64 ci-pairs = 512 -> one pair per thread (MALL loads)
    if (s > 1) {
      const int wi8 = tid >> 6, c2 = tid & 63;
      const int wi = (wi8 < 4) ? wi8 : (wi8 + 16);  // 0..3 and 20..23
      const int p = pos_base - 4 + wi;
      float x0 = 0.f, x1 = 0.f;
      if (p >= 0 && p < WDIM) {
        x0 = dev_load(&data[bbase + (size_t)(2 * c2) * RW + (size_t)rp * WDIM + p]);
        x1 = dev_load(&data[bbase + (size_t)(2 * c2 + 1) * RW + (size_t)rp * WDIM + p]);
      }
      const _Float16 h0 = (_Float16)x0, h1 = (_Float16)x1;
      const _Float16 l0 = (_Float16)(x0 - (float)h0), l1 = (_Float16)(x1 - (float)h1);
      fh[pb * PL + wi * 68 + c2] = pack_h2(h0, h1);
      fl[pb * PL + wi * 68 + c2] = pack_h2(l0, l1);
    }
    __syncthreads();  // (B) planes[pb] complete

    // MFMA: D[co16 x pos16], K = 1152 (36 k-tiles), 3-term split.
    // BIT-EXACT round-3 order: t ascending, 3 separate accumulators.
    f32x4 aA = {0.f, 0.f, 0.f, 0.f}, aB = {0.f, 0.f, 0.f, 0.f}, aC = {0.f, 0.f, 0.f, 0.f};
#pragma unroll
    for (int t = 0; t < 36; ++t) {
      const int dk = t >> 2;
      const int off = pb * PL + (n + dk) * 68 + (t & 3) * 16 + q * 4;  // 16B-aligned
      const f16x8 bh = *(const f16x8*)&fh[off];
      const f16x8 bl = *(const f16x8*)&fl[off];
      const f16x8 al = wloL[(size_t)t * 64];
      aA = __builtin_amdgcn_mfma_f32_16x16x32_f16(ahi[t], bh, aA, 0, 0, 0);
      aB = __builtin_amdgcn_mfma_f32_16x16x32_f16(ahi[t], bl, aB, 0, 0, 0);
      aC = __builtin_amdgcn_mfma_f32_16x16x32_f16(al, bh, aC, 0, 0, 0);
    }

    // epilogue: C/D layout col=lane&15 (pos), row=q*4+reg (co-within-tile).
    // Store to global (sc, for neighbor halos) AND convert own cols directly
    // into planes[cb] (bit-identical to a global round-trip re-conversion).
    float resv[4];
#pragma unroll
    for (int reg = 0; reg < 4; ++reg) {
      const float v = aA[reg] + aB[reg] + aC[reg];
      resv[reg] = (pos < WDIM) ? (cur[reg] + fmaxf(v, 0.f)) : 0.f;
    }
    if (pos < WDIM) {
#pragma unroll
      for (int reg = 0; reg < 4; ++reg) {
        const int co = wave * 16 + q * 4 + reg;
        dev_store(&data[bbase + (size_t)co * RW + (size_t)r * WDIM + pos], resv[reg]);
      }
    }
    {
      const int base = cb * PL + (n + 4) * 68 + wave * 8 + q * 2;
      const _Float16 h0 = (_Float16)resv[0], h1 = (_Float16)resv[1];
      const _Float16 l0 = (_Float16)(resv[0] - (float)h0), l1 = (_Float16)(resv[1] - (float)h1);
      fh[base] = pack_h2(h0, h1);
      fl[base] = pack_h2(l0, l1);
      const _Float16 h2 = (_Float16)resv[2], h3 = (_Float16)resv[3];
      const _Float16 l2 = (_Float16)(resv[2] - (float)h2), l3 = (_Float16)(resv[3] - (float)h3);
      fh[base + 1] = pack_h2(h2, h3);
      fl[base + 1] = pack_h2(l2, l3);
    }
    __syncthreads();  // (C) drains vmcnt -> stores visible before flag
    if (tid == 0)
      __hip_atomic_store(&flags[((size_t)b * RDIM + r) * NCH + jc], 1u, __ATOMIC_RELAXED,
                         __HIP_MEMORY_SCOPE_AGENT);
  }
}

extern "C" void kernel_launch(void* const* d_in, const int* in_sizes, int n_in, void* d_out,
                              int out_size, void* d_ws, size_t ws_size, hipStream_t stream) {
  const float* x = (const float*)d_in[0];
  const float* w_down = (const float*)d_in[1];
  const float* w_up = (const float*)d_in[2];
  const float* w_right = (const float*)d_in[3];
  const float* w_left = (const float*)d_in[4];
  float* out = (float*)d_out;

  // ---- ws layout ----
  // [0, 256K):        flags (memset 0)
  // [256K, 256K+8*294912): weight frag planes (hi,lo) x 4 passes
  // [2,621,440, ...): transpose scratch T if it fits, else reuse d_in[0]
  unsigned* flags = (unsigned*)d_ws;
  unsigned* f_down = flags;                      // 72*13*16 = 14976
  unsigned* f_up = f_down + H_ * 13 * B_;        // 14976
  unsigned* f_right = f_up + H_ * 13 * B_;       // 200*5*16 = 16000
  unsigned* f_left = f_right + W_ * 5 * B_;      // 16000
  hipMemsetAsync(d_ws, 0, 262144, stream);

  const size_t PLANE = (size_t)8 * 36 * 64;  // f16x8 elements per plane = 294912 B
  f16x8* wf = (f16x8*)((char*)d_ws + 262144);
  f16x8* whi_d = wf + 0 * PLANE;
  f16x8* wlo_d = wf + 1 * PLANE;
  f16x8* whi_u = wf + 2 * PLANE;
  f16x8* wlo_u = wf + 3 * PLANE;
  f16x8* whi_r = wf + 4 * PLANE;
  f16x8* wlo_r = wf + 5 * PLANE;
  f16x8* whi_l = wf + 6 * PLANE;
  f16x8* wlo_l = wf + 7 * PLANE;

  const size_t toff = 262144 + 8 * PLANE * sizeof(f16x8);
  const size_t tbytes = (size_t)NTOT * sizeof(float);
  float* T = (ws_size >= toff + tbytes) ? (float*)((char*)d_ws + toff) : (float*)d_in[0];

  // weight repack (one-time per launch)
  repack_w<<<288, 64, 0, stream>>>(w_down, whi_d, wlo_d);
  repack_w<<<288, 64, 0, stream>>>(w_up, whi_u, wlo_u);
  repack_w<<<288, 64, 0, stream>>>(w_right, whi_r, wlo_r);
  repack_w<<<288, 64, 0, stream>>>(w_left, whi_l, wlo_l);

  // out = x
  copy_f4<<<1024, 256, 0, stream>>>((const float4*)x, (float4*)out, NTOT / 4);

  // down/up: scan h (RDIM=72), conv over w (WDIM=200, 13 chunks) -> 208 blocks
  pass_mfma<H_, W_, 13><<<16 * 13, 512, 0, stream>>>(out, whi_d, wlo_d, f_down, +1);
  pass_mfma<H_, W_, 13><<<16 * 13, 512, 0, stream>>>(out, whi_u, wlo_u, f_up, -1);

  // transpose [b,c,h,w] -> [b,c,w,h]
  {
    dim3 g((W_ + 31) / 32, (H_ + 31) / 32, B_ * C_);
    transpose_hw<H_, W_><<<g, dim3(32, 8), 0, stream>>>(out, T);
  }

  // right/left: scan w (RDIM=200), conv over h (WDIM=72, 5 chunks) -> 80 blocks
  pass_mfma<W_, H_, 5><<<16 * 5, 512, 0, stream>>>(T, whi_r, wlo_r, f_right, +1);
  pass_mfma<W_, H_, 5><<<16 * 5, 512, 0, stream>>>(T, whi_l, wlo_l, f_left, -1);

  // transpose back
  {
    dim3 g((H_ + 31) / 32, (W_ + 31) / 32, B_ * C_);
    transpose_hw<W_, H_><<<g, dim3(32, 8), 0, stream>>>(T, out);
  }
}

// Round 6
// 3636.526 us; speedup vs baseline: 2.0631x; 1.2744x over previous
//
#include <hip/hip_runtime.h>
#include <cstdint>
#include <cstddef>

// MessagePassing (SCNN-style): 4 sequential directional scans.
// B=16 C=128 H=72 W=200 K=9 pad=4, fp32 in/out.
//
// Round-3 (PASS 6577us): relaxed agent-scope atomics, 1 block/(b,jc).
// Round-4/5 (FAIL): split (b,jc) ownership across blocks -> do not split.
// Round-6 (PASS 7502us): RELEASE flag regressed; "+v" pin spilled to scratch.
// Round-7 (PASS 4634us): own outputs kept in LDS ping-pong planes; only the
//   8 halo cols fetched via MALL per step. W step 7.47us, H step ~9.0us.
//   Bank-conflict counter is benign (even 8-cy b128 distribution, 2-way free).
// Round-8 (this): kill the per-step weight re-stream + barrier A.
//   - VGPR=128 proves ahi[36] (144 VGPR) still re-fetched from L2 every step
//     (576KB/block-step with wlo); H's 26 blocks/XCD make it ~3.5us/step of
//     L2 BW. Pin whi[0..27] into AGPRs ("+a" pins INSIDE the s-loop): 112
//     AGPR + <=144 VGPR = 256/wave fits 2 waves/SIMD exactly. AGPR class
//     does not fight the 128-VGPR occupancy heuristic (round-6's "+v" did).
//   - Spin fused into halo load: each of 512 threads spins only on the flag
//     its own halo column needs (left wi<4, right wi>=20), then loads.
//     Barrier (A) deleted -> 2 barriers/step; right-halo latency overlaps.
//   - All arithmetic bit-identical to round-7 -> absmax exactly 0.25.

#define B_ 16
#define C_ 128
#define H_ 72
#define W_ 200
#define KW 9
#define NTOT (B_ * C_ * H_ * W_)

using f16x8 = _Float16 __attribute__((ext_vector_type(8)));
using f32x4 = float __attribute__((ext_vector_type(4)));

#define N_AGPR_FRAGS 28  // whi frags pinned to AGPRs (4 AGPR each)

__device__ __forceinline__ unsigned pack_h2(_Float16 lo, _Float16 hi) {
  unsigned short a = __builtin_bit_cast(unsigned short, lo);
  unsigned short b = __builtin_bit_cast(unsigned short, hi);
  return (unsigned)a | ((unsigned)b << 16);
}

// device-coherent (MALL) access, no cache-wide maintenance ops
__device__ __forceinline__ float dev_load(const float* p) {
  return __hip_atomic_load(p, __ATOMIC_RELAXED, __HIP_MEMORY_SCOPE_AGENT);
}
__device__ __forceinline__ void dev_store(float* p, float v) {
  __hip_atomic_store(p, v, __ATOMIC_RELAXED, __HIP_MEMORY_SCOPE_AGENT);
}

// ---------------- copy x -> out ----------------
__global__ void copy_f4(const float4* __restrict__ src, float4* __restrict__ dst, int n4) {
  int i = blockIdx.x * blockDim.x + threadIdx.x;
  const int stride = gridDim.x * blockDim.x;
  for (; i < n4; i += stride) dst[i] = src[i];
}

// ---------------- transpose last two dims ----------------
template <int SH, int SW>
__global__ void transpose_hw(const float* __restrict__ src, float* __restrict__ dst) {
  __shared__ float t[32][33];
  const size_t base = (size_t)blockIdx.z * SH * SW;
  const int x = blockIdx.x * 32 + threadIdx.x;
#pragma unroll
  for (int j = 0; j < 4; ++j) {
    const int y = blockIdx.y * 32 + threadIdx.y + j * 8;
    if (y < SH && x < SW) t[threadIdx.y + j * 8][threadIdx.x] = src[base + (size_t)y * SW + x];
  }
  __syncthreads();
  const int x2 = blockIdx.y * 32 + threadIdx.x;
#pragma unroll
  for (int j = 0; j < 4; ++j) {
    const int y2 = blockIdx.x * 32 + threadIdx.y + j * 8;
    if (y2 < SW && x2 < SH) dst[base + (size_t)y2 * SH + x2] = t[threadIdx.x][threadIdx.y + j * 8];
  }
}

// ---------------- weight repack: wgt[co][ci][dk] -> MFMA A-frag order ----------------
// frag index: [cot(8)][t(36)][lane(64)] f16x8; lane: m=lane&15 (co), q=lane>>4;
// element j <-> k = t*32 + q*8 + j, k = dk*128 + ci (dk = t>>2, ci = (t&3)*32 + q*8 + j)
__global__ void repack_w(const float* __restrict__ wgt, f16x8* __restrict__ whi,
                         f16x8* __restrict__ wlo) {
  const int blk = blockIdx.x;  // cot*36 + t
  const int cot = blk / 36, t = blk % 36;
  const int lane = threadIdx.x;
  const int n = lane & 15, q = lane >> 4;
  const int co = cot * 16 + n, dk = t >> 2, ci0 = (t & 3) * 32 + q * 8;
  f16x8 h, l;
#pragma unroll
  for (int j = 0; j < 8; ++j) {
    const float w = wgt[((size_t)co * C_ + ci0 + j) * KW + dk];
    const _Float16 hh = (_Float16)w;
    h[j] = hh;
    l[j] = (_Float16)(w - (float)hh);
  }
  whi[(size_t)blk * 64 + lane] = h;
  wlo[(size_t)blk * 64 + lane] = l;
}

// ---------------- MFMA scan pass ----------------
// data[b][c][RDIM][WDIM]; scan RDIM rows; conv (K=9,pad4) over contiguous WDIM.
// grid = 16*NCH blocks: b = bx&15, chunk jc = bx>>4 (16 positions).
// fp16 planes ping-pong in LDS: buffer (s&1) holds row r's window slice
// [wi 0..23] = pos [pos_base-4, pos_base+20); own cols wi 4..19 written by
// epilogue from registers; halo wi 0..3 / 20..23 fetched from MALL next step.
template <int RDIM, int WDIM, int NCH>
__global__ __launch_bounds__(512, 1) void pass_mfma(float* __restrict__ data,
                                                    const f16x8* __restrict__ whi,
                                                    const f16x8* __restrict__ wlo,
                                                    unsigned* flags, const int dir) {
  constexpr int RW = RDIM * WDIM;
  constexpr int PL = 24 * 68;  // u32 per plane buffer: [wi(24)][ci-pair pad 68]
  __shared__ __align__(16) unsigned fh[2 * PL];
  __shared__ __align__(16) unsigned fl[2 * PL];

  const int tid = threadIdx.x;
  const int wave = tid >> 6, lane = tid & 63;
  const int n = lane & 15, q = lane >> 4;
  const int b = blockIdx.x & 15, jc = blockIdx.x >> 4;
  const int pos_base = jc * 16;
  const int pos = pos_base + n;
  const size_t bbase = (size_t)b * C_ * RW;

  // persistent A-frags (Whi); first N_AGPR_FRAGS pinned to AGPRs in-loop
  f16x8 ahi[36];
#pragma unroll
  for (int t = 0; t < 36; ++t) ahi[t] = whi[(size_t)(wave * 36 + t) * 64 + lane];
  const f16x8* wloL = wlo + (size_t)wave * 36 * 64 + lane;

  // halo-thread geometry (each of 512 threads owns one (wi, ci-pair))
  const int h_wi8 = tid >> 6, h_c2 = tid & 63;
  const int h_wi = (h_wi8 < 4) ? h_wi8 : (h_wi8 + 16);  // 0..3 and 20..23
  const int h_p = pos_base - 4 + h_wi;
  const bool h_valid = (h_p >= 0 && h_p < WDIM);
  const int h_jn = (h_wi < 4) ? (jc - 1) : (jc + 1);  // producer chunk of h_p

  // ---- init: fill plane buffer 0 with full 24-wi window of row r0 ----
  // row r0 is pre-pass data (written by a previous kernel) -> plain cached.
  {
    const int r0 = (dir > 0) ? 0 : (RDIM - 1);
#pragma unroll
    for (int i = 0; i < 3; ++i) {
      const int idx = tid + 512 * i;  // 1536 = 24 wi * 64 ci-pairs
      const int wi = idx >> 6, c2 = idx & 63;
      const int p = pos_base - 4 + wi;
      float x0 = 0.f, x1 = 0.f;
      if (p >= 0 && p < WDIM) {
        x0 = data[bbase + (size_t)(2 * c2) * RW + (size_t)r0 * WDIM + p];
        x1 = data[bbase + (size_t)(2 * c2 + 1) * RW + (size_t)r0 * WDIM + p];
      }
      const _Float16 h0 = (_Float16)x0, h1 = (_Float16)x1;
      const _Float16 l0 = (_Float16)(x0 - (float)h0), l1 = (_Float16)(x1 - (float)h1);
      fh[wi * 68 + c2] = pack_h2(h0, h1);
      fl[wi * 68 + c2] = pack_h2(l0, l1);
    }
  }
  __syncthreads();  // init fence (was provided by the deleted barrier A)

  for (int s = 1; s < RDIM; ++s) {
    const int r = (dir > 0) ? s : (RDIM - 1 - s);
    const int rp = r - dir;          // producer row
    const int pb = (s - 1) & 1;      // plane buffer holding row rp
    const int cb = s & 1;            // plane buffer to fill with row r

    // AGPR pin: forces whi[0..27] to live in AGPRs across the loop (opaque
    // asm -> no remat; "a" class -> doesn't fight the VGPR occupancy target)
#pragma unroll
    for (int t = 0; t < N_AGPR_FRAGS; ++t) asm volatile("" : "+a"(ahi[t]));

    // preload current row r: no cross-block producer within this pass ->
    // plain cached load; issued before the spin to hide latency.
    float cur[4];
#pragma unroll
    for (int reg = 0; reg < 4; ++reg) {
      const int co = wave * 16 + q * 4 + reg;
      cur[reg] = (pos < WDIM) ? data[bbase + (size_t)co * RW + (size_t)r * WDIM + pos] : 0.f;
    }

    // fused spin + halo fill: each thread waits only on the flag its own
    // halo column needs (control-dependent loads -> ordered after observe).
    if (s > 1) {
      float x0 = 0.f, x1 = 0.f;
      if (h_valid) {
        unsigned* f = &flags[((size_t)b * RDIM + rp) * NCH + h_jn];
        while (__hip_atomic_load(f, __ATOMIC_RELAXED, __HIP_MEMORY_SCOPE_AGENT) == 0u)
          __builtin_amdgcn_s_sleep(1);
        x0 = dev_load(&data[bbase + (size_t)(2 * h_c2) * RW + (size_t)rp * WDIM + h_p]);
        x1 = dev_load(&data[bbase + (size_t)(2 * h_c2 + 1) * RW + (size_t)rp * WDIM + h_p]);
      }
      const _Float16 h0 = (_Float16)x0, h1 = (_Float16)x1;
      const _Float16 l0 = (_Float16)(x0 - (float)h0), l1 = (_Float16)(x1 - (float)h1);
      fh[pb * PL + h_wi * 68 + h_c2] = pack_h2(h0, h1);
      fl[pb * PL + h_wi * 68 + h_c2] = pack_h2(l0, l1);
    }
    __syncthreads();  // (B) planes[pb] complete

    // MFMA: D[co16 x pos16], K = 1152 (36 k-tiles), 3-term split.
    // BIT-EXACT round-7 order: t ascending, 3 separate accumulators.
    f32x4 aA = {0.f, 0.f, 0.f, 0.f}, aB = {0.f, 0.f, 0.f, 0.f}, aC = {0.f, 0.f, 0.f, 0.f};
#pragma unroll
    for (int t = 0; t < 36; ++t) {
      const int dk = t >> 2;
      const int off = pb * PL + (n + dk) * 68 + (t & 3) * 16 + q * 4;  // 16B-aligned
      const f16x8 bh = *(const f16x8*)&fh[off];
      const f16x8 bl = *(const f16x8*)&fl[off];
      const f16x8 al = wloL[(size_t)t * 64];
      aA = __builtin_amdgcn_mfma_f32_16x16x32_f16(ahi[t], bh, aA, 0, 0, 0);
      aB = __builtin_amdgcn_mfma_f32_16x16x32_f16(ahi[t], bl, aB, 0, 0, 0);
      aC = __builtin_amdgcn_mfma_f32_16x16x32_f16(al, bh, aC, 0, 0, 0);
    }

    // epilogue: C/D layout col=lane&15 (pos), row=q*4+reg (co-within-tile).
    // Store to global (sc, for neighbor halos) AND convert own cols directly
    // into planes[cb] (bit-identical to a global round-trip re-conversion).
    float resv[4];
#pragma unroll
    for (int reg = 0; reg < 4; ++reg) {
      const float v = aA[reg] + aB[reg] + aC[reg];
      resv[reg] = (pos < WDIM) ? (cur[reg] + fmaxf(v, 0.f)) : 0.f;
    }
    if (pos < WDIM) {
#pragma unroll
      for (int reg = 0; reg < 4; ++reg) {
        const int co = wave * 16 + q * 4 + reg;
        dev_store(&data[bbase + (size_t)co * RW + (size_t)r * WDIM + pos], resv[reg]);
      }
    }
    {
      const int base = cb * PL + (n + 4) * 68 + wave * 8 + q * 2;
      const _Float16 h0 = (_Float16)resv[0], h1 = (_Float16)resv[1];
      const _Float16 l0 = (_Float16)(resv[0] - (float)h0), l1 = (_Float16)(resv[1] - (float)h1);
      fh[base] = pack_h2(h0, h1);
      fl[base] = pack_h2(l0, l1);
      const _Float16 h2 = (_Float16)resv[2], h3 = (_Float16)resv[3];
      const _Float16 l2 = (_Float16)(resv[2] - (float)h2), l3 = (_Float16)(resv[3] - (float)h3);
      fh[base + 1] = pack_h2(h2, h3);
      fl[base + 1] = pack_h2(l2, l3);
    }
    __syncthreads();  // (C) drains vmcnt -> stores visible before flag
    if (tid == 0)
      __hip_atomic_store(&flags[((size_t)b * RDIM + r) * NCH + jc], 1u, __ATOMIC_RELAXED,
                         __HIP_MEMORY_SCOPE_AGENT);
  }
}

extern "C" void kernel_launch(void* const* d_in, const int* in_sizes, int n_in, void* d_out,
                              int out_size, void* d_ws, size_t ws_size, hipStream_t stream) {
  const float* x = (const float*)d_in[0];
  const float* w_down = (const float*)d_in[1];
  const float* w_up = (const float*)d_in[2];
  const float* w_right = (const float*)d_in[3];
  const float* w_left = (const float*)d_in[4];
  float* out = (float*)d_out;

  // ---- ws layout ----
  // [0, 256K):        flags (memset 0)
  // [256K, 256K+8*294912): weight frag planes (hi,lo) x 4 passes
  // [2,621,440, ...): transpose scratch T if it fits, else reuse d_in[0]
  unsigned* flags = (unsigned*)d_ws;
  unsigned* f_down = flags;                      // 72*13*16 = 14976
  unsigned* f_up = f_down + H_ * 13 * B_;        // 14976
  unsigned* f_right = f_up + H_ * 13 * B_;       // 200*5*16 = 16000
  unsigned* f_left = f_right + W_ * 5 * B_;      // 16000
  hipMemsetAsync(d_ws, 0, 262144, stream);

  const size_t PLANE = (size_t)8 * 36 * 64;  // f16x8 elements per plane = 294912 B
  f16x8* wf = (f16x8*)((char*)d_ws + 262144);
  f16x8* whi_d = wf + 0 * PLANE;
  f16x8* wlo_d = wf + 1 * PLANE;
  f16x8* whi_u = wf + 2 * PLANE;
  f16x8* wlo_u = wf + 3 * PLANE;
  f16x8* whi_r = wf + 4 * PLANE;
  f16x8* wlo_r = wf + 5 * PLANE;
  f16x8* whi_l = wf + 6 * PLANE;
  f16x8* wlo_l = wf + 7 * PLANE;

  const size_t toff = 262144 + 8 * PLANE * sizeof(f16x8);
  const size_t tbytes = (size_t)NTOT * sizeof(float);
  float* T = (ws_size >= toff + tbytes) ? (float*)((char*)d_ws + toff) : (float*)d_in[0];

  // weight repack (one-time per launch)
  repack_w<<<288, 64, 0, stream>>>(w_down, whi_d, wlo_d);
  repack_w<<<288, 64, 0, stream>>>(w_up, whi_u, wlo_u);
  repack_w<<<288, 64, 0, stream>>>(w_right, whi_r, wlo_r);
  repack_w<<<288, 64, 0, stream>>>(w_left, whi_l, wlo_l);

  // out = x
  copy_f4<<<1024, 256, 0, stream>>>((const float4*)x, (float4*)out, NTOT / 4);

  // down/up: scan h (RDIM=72), conv over w (WDIM=200, 13 chunks) -> 208 blocks
  pass_mfma<H_, W_, 13><<<16 * 13, 512, 0, stream>>>(out, whi_d, wlo_d, f_down, +1);
  pass_mfma<H_, W_, 13><<<16 * 13, 512, 0, stream>>>(out, whi_u, wlo_u, f_up, -1);

  // transpose [b,c,h,w] -> [b,c,w,h]
  {
    dim3 g((W_ + 31) / 32, (H_ + 31) / 32, B_ * C_);
    transpose_hw<H_, W_><<<g, dim3(32, 8), 0, stream>>>(out, T);
  }

  // right/left: scan w (RDIM=200), conv over h (WDIM=72, 5 chunks) -> 80 blocks
  pass_mfma<W_, H_, 5><<<16 * 5, 512, 0, stream>>>(T, whi_r, wlo_r, f_right, +1);
  pass_mfma<W_, H_, 5><<<16 * 5, 512, 0, stream>>>(T, whi_l, wlo_l, f_left, -1);

  // transpose back
  {
    dim3 g((H_ + 31) / 32, (W_ + 31) / 32, B_ * C_);
    transpose_hw<W_, H_><<<g, dim3(32, 8), 0, stream>>>(T, out);
  }
}